// Round 8
// baseline (3798.994 us; speedup 1.0000x reference)
//
#include <hip/hip_runtime.h>
#include <hip/hip_bf16.h>

#define B_ 64
#define T_ 256
#define D_ 200
#define H_ 300
#define L_ 8
#define M_ 16384      // T_*B_
#define NG 1800       // 6H
#define NZ 1500       // 5H
#define KP 320        // padded K stride for xb / WbT
#define NBP 2048      // padded N rows for WbT (16*128; rows>=1800 zero)

typedef __attribute__((ext_vector_type(8))) short bf16x8;
typedef __attribute__((ext_vector_type(4))) float f32x4;
typedef __attribute__((ext_vector_type(4))) unsigned u32x4;
typedef unsigned long long ull;

__device__ __forceinline__ unsigned short f2bf(float f) {
  union { float f; unsigned u; } v; v.f = f;
  unsigned r = v.u + 0x7fffu + ((v.u >> 16) & 1u);   // RNE
  return (unsigned short)(r >> 16);
}

__device__ __forceinline__ float sigf(float x) { return 1.f / (1.f + __expf(-x)); }
__device__ __forceinline__ float tanhf_(float x) {
  x = fminf(15.f, fmaxf(-15.f, x));
  float e = __expf(2.f * x);
  return (e - 1.f) / (e + 1.f);
}

// raw barrier: LDS-only wait (no vmcnt drain -> global loads/stores stay in flight)
#define BARRIER() asm volatile("s_waitcnt lgkmcnt(0)\n\ts_barrier" ::: "memory")

// ---- exchange memory helpers ----
__device__ __forceinline__ u32x4 ld128_nt(const ull* p) {
  u32x4 v;
  asm volatile("global_load_dwordx4 %0, %1, off nt\n\ts_waitcnt vmcnt(0)"
               : "=v"(v) : "v"(p) : "memory");
  return v;
}
__device__ __forceinline__ u32x4 ld128_sys(const ull* p) {
  u32x4 v;
  asm volatile("global_load_dwordx4 %0, %1, off sc0 sc1\n\ts_waitcnt vmcnt(0)"
               : "=v"(v) : "v"(p) : "memory");
  return v;
}
__device__ __forceinline__ int ld32_nt(const int* p) {
  int v;
  asm volatile("global_load_dword %0, %1, off nt\n\ts_waitcnt vmcnt(0)"
               : "=v"(v) : "v"(p) : "memory");
  return v;
}
__device__ __forceinline__ int ld32_sys_i(const int* p) {
  int v;
  asm volatile("global_load_dword %0, %1, off sc0 sc1\n\ts_waitcnt vmcnt(0)"
               : "=v"(v) : "v"(p) : "memory");
  return v;
}
__device__ __forceinline__ void st64_plain(ull* p, ull v) {
  asm volatile("global_store_dwordx2 %0, %1, off" :: "v"(p), "v"(v) : "memory");
}
__device__ __forceinline__ void st64_sys(ull* p, ull v) {
  asm volatile("global_store_dwordx2 %0, %1, off sc0 sc1" :: "v"(p), "v"(v) : "memory");
}
__device__ __forceinline__ void st32_plain(int* p, int v) {
  asm volatile("global_store_dword %0, %1, off" :: "v"(p), "v"(v) : "memory");
}
__device__ __forceinline__ void st32_sys_i(int* p, int v) {
  asm volatile("global_store_dword %0, %1, off sc0 sc1" :: "v"(p), "v"(v) : "memory");
}

// async global->LDS, 16B per lane; LDS dest = wave-uniform base + lane*16
__device__ __forceinline__ void gl_lds16(const unsigned short* g, unsigned short* l) {
  __builtin_amdgcn_global_load_lds(
      (const __attribute__((address_space(1))) void*)g,
      (__attribute__((address_space(3))) void*)l, 16, 0, 0);
}

// ---- weight transpose+pad: W[k][n] fp32 -> WbT[l][n][k] bf16, [NBP][KP], zero-padded ----
__global__ void k_transpose_w(const float* __restrict__ W0, const float* __restrict__ Wr,
                              unsigned short* __restrict__ WbT) {
  __shared__ unsigned short t_lds[64][65];
  const int n0 = blockIdx.x * 64;
  const int k0 = blockIdx.y * 64;
  const int l = blockIdx.z;
  const int Kl = (l == 0) ? D_ : H_;
  const float* W = (l == 0) ? W0 : (Wr + (size_t)(l - 1) * H_ * NG);
  unsigned short* out = WbT + (size_t)l * NBP * KP;
  const int tx = threadIdx.x & 63;
  const int ty = threadIdx.x >> 6;     // 0..3
  #pragma unroll
  for (int i = 0; i < 16; i++) {
    int k = k0 + ty * 16 + i;
    int n = n0 + tx;
    float v = (k < Kl && n < NG) ? W[(size_t)k * NG + n] : 0.f;
    t_lds[ty * 16 + i][tx] = f2bf(v);
  }
  __syncthreads();
  #pragma unroll
  for (int i = 0; i < 16; i++) {
    int n = n0 + ty * 16 + i;
    if (n < NG) out[(size_t)n * KP + k0 + tx] = t_lds[tx][ty * 16 + i];
  }
}

// ---- inputs [B,T,D] fp32 -> time-major xb [T*B][KP] bf16 (pad cols zeroed by memset) ----
__global__ void k_transpose_in(const float* __restrict__ inp, unsigned short* __restrict__ xb) {
  int i = blockIdx.x * blockDim.x + threadIdx.x;     // over T_*B_*D_
  if (i >= T_ * B_ * D_) return;
  int d = i % D_;
  int r = i / D_;       // t*B_+b
  int b = r % B_;
  int t = r / B_;
  xb[(size_t)r * KP + d] = f2bf(inp[((size_t)b * T_ + t) * D_ + d]);
}

// ---- hidden[7] [T,B,H] -> output [B,T,H] ----
__global__ void k_out(const float* __restrict__ hid7, float* __restrict__ outp) {
  int i = blockIdx.x * blockDim.x + threadIdx.x;     // over B_*T_*H_
  if (i >= B_ * T_ * H_) return;
  int j = i % H_;
  int r = i / H_;
  int t = r % T_;
  int b = r / T_;
  outp[i] = hid7[((size_t)t * B_ + b) * H_ + j];
}

// ---- pi GEMM (layer 0 only): C[M,1800] = A[M][KP] * Bt (N-major [NBP][KP]) ----
__global__ __launch_bounds__(256) void k_gemm(const unsigned short* __restrict__ A,
                                              const unsigned short* __restrict__ Bt,
                                              float* __restrict__ C, int nk) {
  __shared__ unsigned short As[128 * 32];
  __shared__ unsigned short Bs[128 * 32];
  const int bm = blockIdx.x, bn = blockIdx.y;
  const int tid = threadIdx.x;
  const int lane = tid & 63, wid = tid >> 6;
  const int wm = wid & 1, wn = wid >> 1;
  const int l16 = lane & 15, quad = lane >> 4;
  const int srow = lane >> 2;
  const int sswz = ((lane & 3) ^ (srow & 3)) << 3;
  const int sA = ((quad ^ (l16 & 3)) << 3);
  const size_t arow0 = (size_t)bm * 128;
  const size_t brow0 = (size_t)bn * 128;
  f32x4 acc[4][4] = {};
  for (int kc = 0; kc < nk; kc++) {
    const int k0 = kc << 5;
    #pragma unroll
    for (int r = 0; r < 2; r++) {
      const int rbase = r * 64 + wid * 16;
      gl_lds16(A  + (arow0 + rbase + srow) * KP + k0 + sswz, &As[rbase * 32]);
      gl_lds16(Bt + (brow0 + rbase + srow) * KP + k0 + sswz, &Bs[rbase * 32]);
    }
    asm volatile("s_waitcnt vmcnt(0)" ::: "memory");
    __syncthreads();
    bf16x8 af[4], bfr[4];
    #pragma unroll
    for (int i = 0; i < 4; i++) {
      af[i]  = *(const bf16x8*)&As[(wm * 64 + i * 16 + l16) * 32 + sA];
      bfr[i] = *(const bf16x8*)&Bs[(wn * 64 + i * 16 + l16) * 32 + sA];
    }
    #pragma unroll
    for (int mi = 0; mi < 4; mi++)
      #pragma unroll
      for (int ni = 0; ni < 4; ni++)
        acc[mi][ni] = __builtin_amdgcn_mfma_f32_16x16x32_bf16(af[mi], bfr[ni], acc[mi][ni], 0, 0, 0);
    __syncthreads();
  }
  const int row0 = bm * 128 + wm * 64 + quad * 4;
  const int col0 = bn * 128 + wn * 64 + l16;
  #pragma unroll
  for (int mi = 0; mi < 4; mi++) {
    #pragma unroll
    for (int ni = 0; ni < 4; ni++) {
      int col = col0 + ni * 16;
      if (col < NG) {
        #pragma unroll
        for (int i = 0; i < 4; i++)
          C[(size_t)(row0 + mi * 16 + i) * NG + col] = acc[mi][ni][i];
      }
    }
  }
}

// ================= recurrence helpers =================
struct PiR { float v0, v1, v2, v3, v4, v6; };

__device__ __forceinline__ void pi_pref_row(PiR& r, const float* __restrict__ pi,
                                            int lr, int rev, int ss, int br, int j2) {
  r.v0 = r.v1 = r.v2 = r.v3 = r.v4 = r.v6 = 0.f;
  if (ss < lr) {
    int t = rev ? (lr - 1 - ss) : ss;
    const float* pr = pi + ((size_t)t * B_ + br) * NG;
    r.v0 = pr[j2]; r.v1 = pr[300 + j2]; r.v2 = pr[600 + j2];
    r.v3 = pr[900 + j2]; r.v4 = pr[1200 + j2]; r.v6 = pr[NZ + j2];
  }
}

// ---- fused kernel: blocks 0..191 = recurrence (layer l); blocks 192.. =
// GEMM workers computing pi for layer l+1 from xb as recur produces it.
// R7 exchange: epoch-gated detection. Producers: 50 plain data stores ->
// wave vmcnt(0) drain (data complete in local L2) -> lane0 stores epoch int
// (plain, + sys mirror for workers) -> sys data stores (fallback area) ->
// hid/xb stores -> pi prefetch. Consumers: poll ONE 64B epoch line (lanes
// 0-11/wave, ~60 line-reads/sweep vs 3600 for per-word polling) until all 12
// epochs >= tag, then a single data load with tag VERIFY; any failure drops
// into the R3 self-healing per-word loop (nt + sys probe). Liveness and
// correctness therefore unconditional; epoch is purely a contention filter.
__global__ __launch_bounds__(512, 2) void k_fused(
    float* __restrict__ pi, const float* __restrict__ Whh,
    const float* __restrict__ bias, const int* __restrict__ lens,
    float* __restrict__ hid, unsigned short* __restrict__ xb,
    ull* __restrict__ h_words, int* __restrict__ ep_pl, int* __restrict__ ep_sy,
    const unsigned short* __restrict__ Bt_next, int rev, int tagbase)
{
  const int bid = blockIdx.x;
  const int tid = threadIdx.x;

  if (bid < 192) {
    // ================= recurrence =================
    __shared__ __align__(16) unsigned short h_lds[16 * 328];
    __shared__ __align__(16) float z_lds[128 * 4];
    __shared__ float bias_s[128];
    __shared__ int len_s[4];

    const int g = bid & 15;    // batch group
    const int cb = bid >> 4;   // column block 0..11

    const int lane = tid & 63;
    const int wid = tid >> 6;
    const int l16 = lane & 15;
    const int quad = lane >> 4;

    const int rp = tid / 25;           // gate mapping (tid<50): row-pair 0..1
    const int gj = tid - rp * 25;
    const int j2 = cb * 25 + gj;

    bf16x8 wfrag[10];
    {
      int n = wid * 16 + l16;
      bool vn = n < 125;
      int colw = vn ? ((n / 25) * 300 + cb * 25 + (n % 25)) : 0;
      #pragma unroll
      for (int c = 0; c < 10; c++) {
        bf16x8 f;
        #pragma unroll
        for (int j = 0; j < 8; j++) {
          int k = c * 32 + quad * 8 + j;
          float v = (vn && k < 300) ? Whh[(size_t)k * NZ + colw] : 0.f;
          f[j] = (short)f2bf(v);
        }
        wfrag[c] = f;
      }
    }
    if (tid < 4) len_s[tid] = lens[g * 4 + tid];
    if (tid < 125) bias_s[tid] = bias[(tid / 25) * 300 + cb * 25 + (tid % 25)];
    for (int i = tid; i < 16 * 328; i += 512) h_lds[i] = 0;
    __syncthreads();

    int S = len_s[0];
    S = len_s[1] > S ? len_s[1] : S;
    S = len_s[2] > S ? len_s[2] : S;
    S = len_s[3] > S ? len_s[3] : S;

    ull* hwf = h_words + (size_t)g * 1200;
    ull* hws = h_words + 16 * 1200 + (size_t)g * 1200;
    int* epl = ep_pl + g * 16;          // 64B epoch line, ints 0..11 used
    int* eps = ep_sy + g * 16;
    const int brbase = g * 4;
    float cA = 0.f, cB = 0.f;

    PiR pa, pb;
    int lA = 0, lB = 0;
    if (tid < 50) {
      lA = len_s[2 * rp]; lB = len_s[2 * rp + 1];
      pi_pref_row(pa, pi, lA, rev, 0, brbase + 2 * rp,     j2);
      pi_pref_row(pb, pi, lB, rev, 0, brbase + 2 * rp + 1, j2);
    }

    for (int s = 0; s < S; s++) {
      if (s > 0 && tid >= 64 && tid < 364) {
        const unsigned tg = (unsigned)(tagbase + s);
        const int par = (s & 1) * 600;
        const int pt = tid - 64;
        const ull* pf = hwf + par + 2 * pt;
        const ull* ps = hws + par + 2 * pt;
        u32x4 v;
        bool ok = false;
        // epoch-gated fast path: poll the single epoch line
        for (int it = 0; it < 64; ++it) {
          int e = (lane < 12) ? ld32_nt(epl + lane) : 0x7fffffff;
          ull bal = __ballot(e >= (int)tg);
          if ((bal & 0xFFFull) == 0xFFFull) { ok = true; break; }
        }
        if (ok) {
          v = ld128_nt(pf);                 // data complete in L2 before epoch
          ok = (v.y == tg) && (v.w == tg);  // verify (self-healing)
        }
        if (!ok) {
          int miss = 0;
          for (;;) {
            v = ld128_nt(pf);
            if ((v.y == tg) && (v.w == tg)) break;
            if ((++miss & 31) == 0) {
              v = ld128_sys(ps);            // MALL truth probe
              if ((v.y == tg) && (v.w == tg)) break;
              __builtin_amdgcn_s_sleep(1);
            }
          }
        }
        // stash bf16 payloads into LDS A-operand layout (2 rows per u64 word)
        int w0 = pt << 1;
        int r2 = (w0 >= 300) ? 1 : 0;
        int k = w0 - r2 * 300;
        h_lds[(2 * r2) * 328 + k]     = (unsigned short)(v.x >> 16);
        h_lds[(2 * r2 + 1) * 328 + k] = (unsigned short)(v.x & 0xffffu);
        int w1 = w0 + 1;
        int r2b = (w1 >= 300) ? 1 : 0;
        int kb = w1 - r2b * 300;
        h_lds[(2 * r2b) * 328 + kb]     = (unsigned short)(v.z >> 16);
        h_lds[(2 * r2b + 1) * 328 + kb] = (unsigned short)(v.z & 0xffffu);
      }
      BARRIER();

      // ---- MFMA: 4 independent chains to cut dependency latency ----
      {
        f32x4 a0 = {0,0,0,0}, a1 = {0,0,0,0}, a2 = {0,0,0,0}, a3 = {0,0,0,0};
        const unsigned short* abase = &h_lds[l16 * 328 + quad * 8];
        #pragma unroll
        for (int c = 0; c < 10; c += 4) {
          bf16x8 h0 = *(const bf16x8*)(abase + c * 32);
          bf16x8 h1 = *(const bf16x8*)(abase + c * 32 + 32);
          a0 = __builtin_amdgcn_mfma_f32_16x16x32_bf16(h0, wfrag[c],     a0, 0, 0, 0);
          a1 = __builtin_amdgcn_mfma_f32_16x16x32_bf16(h1, wfrag[c + 1], a1, 0, 0, 0);
          if (c + 2 < 10) {
            bf16x8 h2 = *(const bf16x8*)(abase + c * 32 + 64);
            bf16x8 h3 = *(const bf16x8*)(abase + c * 32 + 96);
            a2 = __builtin_amdgcn_mfma_f32_16x16x32_bf16(h2, wfrag[c + 2], a2, 0, 0, 0);
            a3 = __builtin_amdgcn_mfma_f32_16x16x32_bf16(h3, wfrag[c + 3], a3, 0, 0, 0);
          }
        }
        f32x4 acc = (a0 + a1) + (a2 + a3);
        if (quad == 0) {
          int n = wid * 16 + l16;
          *(f32x4*)&z_lds[n * 4] = acc;
        }
      }
      BARRIER();

      if (tid < 50) {
        __builtin_amdgcn_s_setprio(1);
        const float bb0 = bias_s[gj],      bb1 = bias_s[25 + gj], bb2 = bias_s[50 + gj];
        const float bb3 = bias_s[75 + gj], bb4 = bias_s[100 + gj];
        const float2 z0 = *(const float2*)&z_lds[(gj      ) * 4 + 2 * rp];
        const float2 z1 = *(const float2*)&z_lds[(25 + gj ) * 4 + 2 * rp];
        const float2 z2 = *(const float2*)&z_lds[(50 + gj ) * 4 + 2 * rp];
        const float2 z3 = *(const float2*)&z_lds[(75 + gj ) * 4 + 2 * rp];
        const float2 z4 = *(const float2*)&z_lds[(100 + gj) * 4 + 2 * rp];
        float iA = sigf(z0.x + pa.v0 + bb0);
        float fA = sigf(z1.x + pa.v1 + bb1);
        float gA = tanhf_(z2.x + pa.v2 + bb2);
        float oA = sigf(z3.x + pa.v3 + bb3);
        float rA = sigf(z4.x + pa.v4 + bb4);
        float cnA = iA * gA + fA * cA; cA = cnA;
        float hA = rA * (oA * tanhf_(cnA)) + (1.f - rA) * pa.v6;
        float iB = sigf(z0.y + pb.v0 + bb0);
        float fB = sigf(z1.y + pb.v1 + bb1);
        float gB = tanhf_(z2.y + pb.v2 + bb2);
        float oB = sigf(z3.y + pb.v3 + bb3);
        float rB = sigf(z4.y + pb.v4 + bb4);
        float cnB = iB * gB + fB * cB; cB = cnB;
        float hB = rB * (oB * tanhf_(cnB)) + (1.f - rB) * pb.v6;

        unsigned short hbA = f2bf(hA), hbB = f2bf(hB);
        ull word = ((ull)(unsigned)(tagbase + s + 1) << 32)
                 | ((unsigned)hbA << 16) | (unsigned)hbB;
        int pidx = ((s + 1) & 1) * 600 + rp * 300 + j2;
        st64_plain(hwf + pidx, word);                       // fast data
        asm volatile("s_waitcnt vmcnt(0)" ::: "memory");    // data complete in L2
        if (tid == 0) {
          st32_plain(epl + cb, tagbase + s + 1);            // epoch (consumers)
          st32_sys_i(eps + cb, tagbase + s + 1);            // sys mirror (workers)
        }
        st64_sys(hws + pidx, word);                         // fallback data (MALL)
        if (s < lA) {
          int t = rev ? (lA - 1 - s) : s;
          int br = brbase + 2 * rp;
          hid[((size_t)t * B_ + br) * H_ + j2] = hA;
          xb[((size_t)t * B_ + br) * KP + j2] = hbA;
        }
        if (s < lB) {
          int t = rev ? (lB - 1 - s) : s;
          int br = brbase + 2 * rp + 1;
          hid[((size_t)t * B_ + br) * H_ + j2] = hB;
          xb[((size_t)t * B_ + br) * KP + j2] = hbB;
        }
        pi_pref_row(pa, pi, lA, rev, s + 1, brbase + 2 * rp,     j2);
        pi_pref_row(pb, pi, lB, rev, s + 1, brbase + 2 * rp + 1, j2);
        __builtin_amdgcn_s_setprio(0);
      }
    }
    if (tid == 0) {
      asm volatile("s_waitcnt vmcnt(0)" ::: "memory");     // all xb stores complete
      st32_plain(epl + cb, tagbase + 299);                 // sentinel
      st32_sys_i(eps + cb, tagbase + 299);
    }
  } else {
    // ================= GEMM workers: pi for layer l+1 =================
    __shared__ unsigned short As[128 * 32];
    __shared__ unsigned short Bs2[2][128 * 32];
    const int w = bid - 192;              // 0..63
    const int cls = w & 7;                // XCD class
    const int k8 = w >> 3;                // 0..7
    const int g = (k8 < 4) ? cls : cls + 8;
    const int q = k8 & 3;                 // col-pairs {2q, 2q+1}
    const int lane = tid & 63;
    const int wid = tid >> 6;             // 0..7
    const int wg = tid >> 8;              // 0/1 -> col-tile half
    const int w4 = wid & 3;
    const int l16 = lane & 15, quad = lane >> 4;
    const int srow = lane >> 2;
    const int sswz = ((lane & 3) ^ (srow & 3)) << 3;
    const int sA = ((quad ^ (l16 & 3)) << 3);
    const int wm = w4 & 1, wn = w4 >> 1;
    const int Sg = lens[4 * g];           // lengths sorted desc -> group max

    for (int ci = 0; ci < 8; ci++) {
      const int chunk = rev ? (7 - ci) : ci;
      const int t0 = chunk * 32;
      int need = rev ? (Sg - t0 + 1) : (t0 + 33);
      if (t0 >= Sg) need = 0;             // all rows stale (beyond lengths)
      if (need > 0) {
        if (tid == 0) {
          const int target = tagbase + need;     // sentinel tagbase+299 covers all
          int iters = 0;
          for (;;) {
            int mn = 0x7fffffff;
            for (int cbx = 0; cbx < 12; cbx++) {
              int v = (iters < 256) ? ld32_nt(ep_pl + g * 16 + cbx)
                                    : ld32_sys_i(ep_sy + g * 16 + cbx);
              mn = v < mn ? v : mn;
            }
            if (mn >= target) break;
            iters++;
            __builtin_amdgcn_s_sleep(8);
          }
        }
        __syncthreads();
      }
      #pragma unroll 1
      for (int cpi = 0; cpi < 2; cpi++) {
        const int cp = 2 * q + cpi;       // 0..7 (256 cols each)
        const unsigned short* BtB = Bt_next + (size_t)(cp * 256 + wg * 128) * KP;
        f32x4 acc[4][4] = {};
        for (int kc = 0; kc < 10; kc++) {
          const int k0 = kc << 5;
          {
            int rl = wid * 16 + srow;     // local row 0..127
            int xrow = (t0 + (rl >> 2)) * 64 + g * 4 + (rl & 3);
            gl_lds16(xb + (size_t)xrow * KP + k0 + sswz, &As[(wid * 16) * 32]);
          }
          #pragma unroll
          for (int r = 0; r < 2; r++) {
            int rbase = w4 * 32 + r * 16;
            gl_lds16(BtB + (size_t)(rbase + srow) * KP + k0 + sswz, &Bs2[wg][rbase * 32]);
          }
          asm volatile("s_waitcnt vmcnt(0)" ::: "memory");
          __syncthreads();
          bf16x8 af[4], bfr[4];
          #pragma unroll
          for (int i = 0; i < 4; i++) {
            af[i]  = *(const bf16x8*)&As[(wm * 64 + i * 16 + l16) * 32 + sA];
            bfr[i] = *(const bf16x8*)&Bs2[wg][(wn * 64 + i * 16 + l16) * 32 + sA];
          }
          #pragma unroll
          for (int mi = 0; mi < 4; mi++)
            #pragma unroll
            for (int ni = 0; ni < 4; ni++)
              acc[mi][ni] = __builtin_amdgcn_mfma_f32_16x16x32_bf16(af[mi], bfr[ni], acc[mi][ni], 0, 0, 0);
          __syncthreads();
        }
        #pragma unroll
        for (int mi = 0; mi < 4; mi++) {
          #pragma unroll
          for (int ni = 0; ni < 4; ni++) {
            int col = cp * 256 + wg * 128 + wn * 64 + ni * 16 + l16;
            if (col < NG) {
              #pragma unroll
              for (int i = 0; i < 4; i++) {
                int rl = wm * 64 + mi * 16 + quad * 4 + i;
                int prow = (t0 + (rl >> 2)) * 64 + g * 4 + (rl & 3);
                pi[(size_t)prow * NG + col] = acc[mi][ni][i];
              }
            }
          }
        }
      }
    }
  }
}

extern "C" void kernel_launch(void* const* d_in, const int* in_sizes, int n_in,
                              void* d_out, int out_size, void* d_ws, size_t ws_size,
                              hipStream_t stream) {
  const float* inputs = (const float*)d_in[0];
  const int* lengths = (const int*)d_in[1];
  const float* W_ih0 = (const float*)d_in[2];
  const float* W_ih_rest = (const float*)d_in[3];
  const float* W_hh = (const float*)d_in[4];
  const float* b_hh = (const float*)d_in[5];
  float* outp = (float*)d_out;
  float* hidden = outp + (size_t)B_ * T_ * H_;   // [L][T,B,H]

  char* ws = (char*)d_ws;
  float* pi = (float*)ws;                                         // M_*NG fp32 (118MB)
  size_t off = (size_t)M_ * NG * 4;
  unsigned short* xb = (unsigned short*)(ws + off);               // M_*KP bf16 (10.5MB)
  off += (size_t)M_ * KP * 2;
  unsigned short* WbT = (unsigned short*)(ws + off);              // 8*NBP*KP bf16 (10.5MB)
  off += (size_t)L_ * NBP * KP * 2;
  ull* h_words = (ull*)(ws + off);   // fast[16][1200] + slow[16][1200] u64 + epochs
  size_t data_bytes = 32ull * 1200 * 8;
  int* ep_pl = (int*)(ws + off + data_bytes);          // [16][16] ints (64B lines)
  int* ep_sy = ep_pl + 16 * 16;                        // [16][16] ints (sys mirror)
  size_t hw_bytes = data_bytes + 2ull * 16 * 16 * 4;
  off += hw_bytes;

  hipMemsetAsync(d_out, 0, (size_t)out_size * 4, stream);         // zero padding regions
  hipMemsetAsync(h_words, 0, hw_bytes, stream);                   // clear tags + epochs
  hipMemsetAsync(xb, 0, (size_t)M_ * KP * 2, stream);             // zero K padding
  hipMemsetAsync(WbT, 0, (size_t)L_ * NBP * KP * 2, stream);      // zero N/K padding

  k_transpose_w<<<dim3(29, 5, 8), 256, 0, stream>>>(W_ih0, W_ih_rest, WbT);
  {
    int n = T_ * B_ * D_;
    k_transpose_in<<<(n + 255) / 256, 256, 0, stream>>>(inputs, xb);
  }
  // layer-0 pi: standalone GEMM (K=200 -> nk=7)
  k_gemm<<<dim3(M_ / 128, 15), 256, 0, stream>>>(xb, WbT, pi, 7);
  for (int l = 0; l < L_; l++) {
    float* hid_l = hidden + (size_t)l * T_ * B_ * H_;
    const unsigned short* Bt_next = WbT + (size_t)(l + 1) * NBP * KP;  // unused when l==7
    int grid = (l < L_ - 1) ? 256 : 192;
    k_fused<<<grid, 512, 0, stream>>>(pi, W_hh + (size_t)l * H_ * NZ, b_hh + (size_t)l * NZ,
                                      lengths, hid_l, xb, h_words, ep_pl, ep_sy,
                                      Bt_next, l & 1, l * 300);
  }
  k_out<<<((B_ * T_ * H_) + 255) / 256, 256, 0, stream>>>(
      hidden + (size_t)(L_ - 1) * T_ * B_ * H_, outp);
}

// Round 9
// 3220.441 us; speedup vs baseline: 1.1797x; 1.1797x over previous
//
#include <hip/hip_runtime.h>
#include <hip/hip_bf16.h>

#define B_ 64
#define T_ 256
#define D_ 200
#define H_ 300
#define L_ 8
#define M_ 16384      // T_*B_
#define NG 1800       // 6H
#define NZ 1500       // 5H
#define KP 320        // padded K stride for xb / WbT
#define NBP 2048      // padded N rows for WbT (16*128; rows>=1800 zero)

typedef __attribute__((ext_vector_type(8))) short bf16x8;
typedef __attribute__((ext_vector_type(4))) float f32x4;
typedef __attribute__((ext_vector_type(4))) unsigned u32x4;
typedef unsigned long long ull;

__device__ __forceinline__ unsigned short f2bf(float f) {
  union { float f; unsigned u; } v; v.f = f;
  unsigned r = v.u + 0x7fffu + ((v.u >> 16) & 1u);   // RNE
  return (unsigned short)(r >> 16);
}

__device__ __forceinline__ float sigf(float x) { return 1.f / (1.f + __expf(-x)); }
__device__ __forceinline__ float tanhf_(float x) {
  x = fminf(15.f, fmaxf(-15.f, x));
  float e = __expf(2.f * x);
  return (e - 1.f) / (e + 1.f);
}

// raw barrier: LDS-only wait (no vmcnt drain -> global loads/stores stay in flight)
#define BARRIER() asm volatile("s_waitcnt lgkmcnt(0)\n\ts_barrier" ::: "memory")

// ---- exchange memory helpers ----
__device__ __forceinline__ u32x4 ld128_nt(const ull* p) {
  u32x4 v;
  asm volatile("global_load_dwordx4 %0, %1, off nt\n\ts_waitcnt vmcnt(0)"
               : "=v"(v) : "v"(p) : "memory");
  return v;
}
__device__ __forceinline__ u32x4 ld128_sys(const ull* p) {
  u32x4 v;
  asm volatile("global_load_dwordx4 %0, %1, off sc0 sc1\n\ts_waitcnt vmcnt(0)"
               : "=v"(v) : "v"(p) : "memory");
  return v;
}
__device__ __forceinline__ int ld32_nt(const int* p) {
  int v;
  asm volatile("global_load_dword %0, %1, off nt\n\ts_waitcnt vmcnt(0)"
               : "=v"(v) : "v"(p) : "memory");
  return v;
}
__device__ __forceinline__ void st64_plain(ull* p, ull v) {
  asm volatile("global_store_dwordx2 %0, %1, off" :: "v"(p), "v"(v) : "memory");
}
__device__ __forceinline__ void st64_sys(ull* p, ull v) {
  asm volatile("global_store_dwordx2 %0, %1, off sc0 sc1" :: "v"(p), "v"(v) : "memory");
}

// async global->LDS, 16B per lane; LDS dest = wave-uniform base + lane*16
__device__ __forceinline__ void gl_lds16(const unsigned short* g, unsigned short* l) {
  __builtin_amdgcn_global_load_lds(
      (const __attribute__((address_space(1))) void*)g,
      (__attribute__((address_space(3))) void*)l, 16, 0, 0);
}

// ---- weight transpose+pad: W[k][n] fp32 -> WbT[l][n][k] bf16, [NBP][KP], zero-padded ----
__global__ void k_transpose_w(const float* __restrict__ W0, const float* __restrict__ Wr,
                              unsigned short* __restrict__ WbT) {
  __shared__ unsigned short t_lds[64][65];
  const int n0 = blockIdx.x * 64;
  const int k0 = blockIdx.y * 64;
  const int l = blockIdx.z;
  const int Kl = (l == 0) ? D_ : H_;
  const float* W = (l == 0) ? W0 : (Wr + (size_t)(l - 1) * H_ * NG);
  unsigned short* out = WbT + (size_t)l * NBP * KP;
  const int tx = threadIdx.x & 63;
  const int ty = threadIdx.x >> 6;     // 0..3
  #pragma unroll
  for (int i = 0; i < 16; i++) {
    int k = k0 + ty * 16 + i;
    int n = n0 + tx;
    float v = (k < Kl && n < NG) ? W[(size_t)k * NG + n] : 0.f;
    t_lds[ty * 16 + i][tx] = f2bf(v);
  }
  __syncthreads();
  #pragma unroll
  for (int i = 0; i < 16; i++) {
    int n = n0 + ty * 16 + i;
    if (n < NG) out[(size_t)n * KP + k0 + tx] = t_lds[tx][ty * 16 + i];
  }
}

// ---- inputs [B,T,D] fp32 -> time-major xb [T*B][KP] bf16 (pad cols zeroed by memset) ----
__global__ void k_transpose_in(const float* __restrict__ inp, unsigned short* __restrict__ xb) {
  int i = blockIdx.x * blockDim.x + threadIdx.x;     // over T_*B_*D_
  if (i >= T_ * B_ * D_) return;
  int d = i % D_;
  int r = i / D_;       // t*B_+b
  int b = r % B_;
  int t = r / B_;
  xb[(size_t)r * KP + d] = f2bf(inp[((size_t)b * T_ + t) * D_ + d]);
}

// ---- hidden[7] [T,B,H] -> output [B,T,H] ----
__global__ void k_out(const float* __restrict__ hid7, float* __restrict__ outp) {
  int i = blockIdx.x * blockDim.x + threadIdx.x;     // over B_*T_*H_
  if (i >= B_ * T_ * H_) return;
  int j = i % H_;
  int r = i / H_;
  int t = r % T_;
  int b = r / T_;
  outp[i] = hid7[((size_t)t * B_ + b) * H_ + j];
}

// ---- pi GEMM (layer 0 only): C[M,1800] = A[M][KP] * Bt (N-major [NBP][KP]) ----
__global__ __launch_bounds__(256) void k_gemm(const unsigned short* __restrict__ A,
                                              const unsigned short* __restrict__ Bt,
                                              float* __restrict__ C, int nk) {
  __shared__ unsigned short As[128 * 32];
  __shared__ unsigned short Bs[128 * 32];
  const int bm = blockIdx.x, bn = blockIdx.y;
  const int tid = threadIdx.x;
  const int lane = tid & 63, wid = tid >> 6;
  const int wm = wid & 1, wn = wid >> 1;
  const int l16 = lane & 15, quad = lane >> 4;
  const int srow = lane >> 2;
  const int sswz = ((lane & 3) ^ (srow & 3)) << 3;
  const int sA = ((quad ^ (l16 & 3)) << 3);
  const size_t arow0 = (size_t)bm * 128;
  const size_t brow0 = (size_t)bn * 128;
  f32x4 acc[4][4] = {};
  for (int kc = 0; kc < nk; kc++) {
    const int k0 = kc << 5;
    #pragma unroll
    for (int r = 0; r < 2; r++) {
      const int rbase = r * 64 + wid * 16;
      gl_lds16(A  + (arow0 + rbase + srow) * KP + k0 + sswz, &As[rbase * 32]);
      gl_lds16(Bt + (brow0 + rbase + srow) * KP + k0 + sswz, &Bs[rbase * 32]);
    }
    asm volatile("s_waitcnt vmcnt(0)" ::: "memory");
    __syncthreads();
    bf16x8 af[4], bfr[4];
    #pragma unroll
    for (int i = 0; i < 4; i++) {
      af[i]  = *(const bf16x8*)&As[(wm * 64 + i * 16 + l16) * 32 + sA];
      bfr[i] = *(const bf16x8*)&Bs[(wn * 64 + i * 16 + l16) * 32 + sA];
    }
    #pragma unroll
    for (int mi = 0; mi < 4; mi++)
      #pragma unroll
      for (int ni = 0; ni < 4; ni++)
        acc[mi][ni] = __builtin_amdgcn_mfma_f32_16x16x32_bf16(af[mi], bfr[ni], acc[mi][ni], 0, 0, 0);
    __syncthreads();
  }
  const int row0 = bm * 128 + wm * 64 + quad * 4;
  const int col0 = bn * 128 + wn * 64 + l16;
  #pragma unroll
  for (int mi = 0; mi < 4; mi++) {
    #pragma unroll
    for (int ni = 0; ni < 4; ni++) {
      int col = col0 + ni * 16;
      if (col < NG) {
        #pragma unroll
        for (int i = 0; i < 4; i++)
          C[(size_t)(row0 + mi * 16 + i) * NG + col] = acc[mi][ni][i];
      }
    }
  }
}

// ================= recurrence helpers =================
struct PiR { float v0, v1, v2, v3, v4, v6; };

// single-row pi prefetch (6 scattered loads, in flight across the next step)
__device__ __forceinline__ void pi_pref6(PiR& r, const float* __restrict__ pi,
                                         int lr, int rev, int ss, int br, int j2) {
  r.v0 = r.v1 = r.v2 = r.v3 = r.v4 = r.v6 = 0.f;
  if (ss < lr) {
    int t = rev ? (lr - 1 - ss) : ss;
    const float* pr = pi + ((size_t)t * B_ + br) * NG;
    r.v0 = pr[j2]; r.v1 = pr[300 + j2]; r.v2 = pr[600 + j2];
    r.v3 = pr[900 + j2]; r.v4 = pr[1200 + j2]; r.v6 = pr[NZ + j2];
  }
}

__device__ __forceinline__ void poll_stash(unsigned tg, int par, int pt,
                                           const ull* hwf, const ull* hws,
                                           unsigned short* h_lds) {
  const ull* pf = hwf + par + 2 * pt;
  const ull* ps = hws + par + 2 * pt;
  u32x4 v;
  int miss = 0;
  for (;;) {
    v = ld128_nt(pf);                                   // local-L2 fast probe
    if ((v.y == tg) && (v.w == tg)) break;
    if ((++miss & 31) == 0) {
      v = ld128_sys(ps);                                // MALL truth probe
      if ((v.y == tg) && (v.w == tg)) break;
      __builtin_amdgcn_s_sleep(1);
    }
  }
  int w0 = pt << 1;
  int r2 = (w0 >= 300) ? 1 : 0;
  int k = w0 - r2 * 300;
  h_lds[(2 * r2) * 328 + k]     = (unsigned short)(v.x >> 16);
  h_lds[(2 * r2 + 1) * 328 + k] = (unsigned short)(v.x & 0xffffu);
  int w1 = w0 + 1;
  int r2b = (w1 >= 300) ? 1 : 0;
  int kb = w1 - r2b * 300;
  h_lds[(2 * r2b) * 328 + kb]     = (unsigned short)(v.z >> 16);
  h_lds[(2 * r2b + 1) * 328 + kb] = (unsigned short)(v.z & 0xffffu);
}

// ---- fused kernel: blocks 0..191 = recurrence (layer l); blocks 192.. =
// GEMM workers computing pi for layer l+1 from xb as recur produces it.
// R8: exchange reverted to R6 (direct dual-publish + nt/sys data poll; epoch
// scheme removed — R7 measured it as +533cy/step of added serial legs).
// Gates split across TWO waves, ONE batch row per lane (waves 0/1 = row-pairs
// {0,1}/{2,3}); u64 pack via intra-wave __shfl from the partner lane. Publish
// issues ~100-150cy earlier; transcendental chain halves. prog protocol: wave0
// drains at gates start (covers its own prior xb stores + prog order), wave1
// drains at phase 1 (idle there), ordered before prog by the mid barrier.
__global__ __launch_bounds__(512, 2) void k_fused(
    float* __restrict__ pi, const float* __restrict__ Whh,
    const float* __restrict__ bias, const int* __restrict__ lens,
    float* __restrict__ hid, unsigned short* __restrict__ xb,
    ull* __restrict__ h_words, int* __restrict__ prog,
    const unsigned short* __restrict__ Bt_next, int rev, int tagbase)
{
  const int bid = blockIdx.x;
  const int tid = threadIdx.x;

  if (bid < 192) {
    // ================= recurrence =================
    __shared__ __align__(16) unsigned short h_lds[16 * 328];
    __shared__ __align__(16) float z_lds[128 * 4];
    __shared__ float bias_s[128];
    __shared__ int len_s[4];

    const int g = bid & 15;    // batch group
    const int cb = bid >> 4;   // column block 0..11

    const int lane = tid & 63;
    const int wid = tid >> 6;
    const int l16 = lane & 15;
    const int quad = lane >> 4;

    // gate mapping: waves 0,1; one batch row per lane
    const int gw = wid;                          // gate wave = row-pair index
    const bool is_gate = (gw < 2) && (lane < 50);
    const int grow = gw * 2 + (lane >= 25 ? 1 : 0);      // batch row 0..3
    const int gcol = (lane >= 25) ? lane - 25 : lane;    // 0..24
    const int j2 = cb * 25 + gcol;

    bf16x8 wfrag[10];
    {
      int n = wid * 16 + l16;
      bool vn = n < 125;
      int colw = vn ? ((n / 25) * 300 + cb * 25 + (n % 25)) : 0;
      #pragma unroll
      for (int c = 0; c < 10; c++) {
        bf16x8 f;
        #pragma unroll
        for (int j = 0; j < 8; j++) {
          int k = c * 32 + quad * 8 + j;
          float v = (vn && k < 300) ? Whh[(size_t)k * NZ + colw] : 0.f;
          f[j] = (short)f2bf(v);
        }
        wfrag[c] = f;
      }
    }
    if (tid < 4) len_s[tid] = lens[g * 4 + tid];
    if (tid < 125) bias_s[tid] = bias[(tid / 25) * 300 + cb * 25 + (tid % 25)];
    for (int i = tid; i < 16 * 328; i += 512) h_lds[i] = 0;
    __syncthreads();

    int S = len_s[0];
    S = len_s[1] > S ? len_s[1] : S;
    S = len_s[2] > S ? len_s[2] : S;
    S = len_s[3] > S ? len_s[3] : S;

    ull* hwf = h_words + (size_t)g * 1200;
    ull* hws = h_words + 16 * 1200 + (size_t)g * 1200;
    const int brbase = g * 4;
    float cr = 0.f;                     // cell state for this lane's row

    PiR pa;
    int lr = 0;
    if (is_gate) {
      lr = len_s[grow];
      pi_pref6(pa, pi, lr, rev, 0, brbase + grow, j2);
    }

    for (int s = 0; s < S; s++) {
      if (s > 0) {
        if (tid >= 128 && tid < 428)
          poll_stash((unsigned)(tagbase + s), (s & 1) * 600, tid - 128, hwf, hws, h_lds);
        else if (tid >= 64 && tid < 128)
          asm volatile("s_waitcnt vmcnt(0)" ::: "memory");  // wave1: drain prior stores
      }
      BARRIER();

      // ---- MFMA: 4 independent chains to cut dependency latency ----
      {
        f32x4 a0 = {0,0,0,0}, a1 = {0,0,0,0}, a2 = {0,0,0,0}, a3 = {0,0,0,0};
        if (s > 0) {
          const unsigned short* abase = &h_lds[l16 * 328 + quad * 8];
          #pragma unroll
          for (int c = 0; c < 10; c += 4) {
            bf16x8 h0 = *(const bf16x8*)(abase + c * 32);
            bf16x8 h1 = *(const bf16x8*)(abase + c * 32 + 32);
            a0 = __builtin_amdgcn_mfma_f32_16x16x32_bf16(h0, wfrag[c],     a0, 0, 0, 0);
            a1 = __builtin_amdgcn_mfma_f32_16x16x32_bf16(h1, wfrag[c + 1], a1, 0, 0, 0);
            if (c + 2 < 10) {
              bf16x8 h2 = *(const bf16x8*)(abase + c * 32 + 64);
              bf16x8 h3 = *(const bf16x8*)(abase + c * 32 + 96);
              a2 = __builtin_amdgcn_mfma_f32_16x16x32_bf16(h2, wfrag[c + 2], a2, 0, 0, 0);
              a3 = __builtin_amdgcn_mfma_f32_16x16x32_bf16(h3, wfrag[c + 3], a3, 0, 0, 0);
            }
          }
        }
        f32x4 acc = (a0 + a1) + (a2 + a3);
        if (quad == 0) {
          int n = wid * 16 + l16;
          *(f32x4*)&z_lds[n * 4] = acc;
        }
      }
      BARRIER();

      if (is_gate) {
        __builtin_amdgcn_s_setprio(1);
        // wave-level drain: completes this wave's prior xb/hid stores (a full
        // step old, ~free) and the pi prefetch loads consumed below. Orders
        // wave0's xb<=s-1 before the prog store (in-order VMEM per wave).
        asm volatile("s_waitcnt vmcnt(0)" ::: "memory");
        const float bb0 = bias_s[gcol],      bb1 = bias_s[25 + gcol];
        const float bb2 = bias_s[50 + gcol], bb3 = bias_s[75 + gcol];
        const float bb4 = bias_s[100 + gcol];
        float z0 = z_lds[(gcol      ) * 4 + grow];
        float z1 = z_lds[(25 + gcol ) * 4 + grow];
        float z2 = z_lds[(50 + gcol ) * 4 + grow];
        float z3 = z_lds[(75 + gcol ) * 4 + grow];
        float z4 = z_lds[(100 + gcol) * 4 + grow];
        float ii = sigf(z0 + pa.v0 + bb0);
        float ff = sigf(z1 + pa.v1 + bb1);
        float gg = tanhf_(z2 + pa.v2 + bb2);
        float oo = sigf(z3 + pa.v3 + bb3);
        float rr = sigf(z4 + pa.v4 + bb4);
        float cn = ii * gg + ff * cr; cr = cn;
        float h = rr * (oo * tanhf_(cn)) + (1.f - rr) * pa.v6;
        unsigned short hb = f2bf(h);
        // partner lane (lane+25) holds the odd row's hb
        unsigned hbO = (unsigned)__shfl((int)(unsigned)hb, lane + 25);
        if (lane < 25) {
          ull word = ((ull)(unsigned)(tagbase + s + 1) << 32)
                   | ((unsigned)hb << 16) | (hbO & 0xffffu);
          int pidx = ((s + 1) & 1) * 600 + gw * 300 + j2;
          st64_plain(hwf + pidx, word);   // fast: local-L2 visible
          st64_sys(hws + pidx, word);     // slow: MALL visible (always correct)
        }
        if (tid == 0) prog[g * 12 + cb] = tagbase + s + 1;   // xb<=s-1 safe
        if (s < lr) {
          int t = rev ? (lr - 1 - s) : s;
          int br = brbase + grow;
          hid[((size_t)t * B_ + br) * H_ + j2] = h;
          xb[((size_t)t * B_ + br) * KP + j2] = hb;
        }
        pi_pref6(pa, pi, lr, rev, s + 1, brbase + grow, j2);
        __builtin_amdgcn_s_setprio(0);
      }
    }
    if (tid >= 64 && tid < 128)
      asm volatile("s_waitcnt vmcnt(0)" ::: "memory");       // wave1 xb complete
    __syncthreads();
    if (tid == 0) {
      asm volatile("s_waitcnt vmcnt(0)" ::: "memory");       // wave0 xb complete
      prog[g * 12 + cb] = tagbase + 299;                     // sentinel
    }
  } else {
    // ================= GEMM workers: pi for layer l+1 =================
    __shared__ unsigned short As[128 * 32];
    __shared__ unsigned short Bs2[2][128 * 32];
    const int w = bid - 192;              // 0..63
    const int cls = w & 7;                // XCD class
    const int k8 = w >> 3;                // 0..7
    const int g = (k8 < 4) ? cls : cls + 8;
    const int q = k8 & 3;                 // col-pairs {2q, 2q+1}
    const int lane = tid & 63;
    const int wid = tid >> 6;             // 0..7
    const int wg = tid >> 8;              // 0/1 -> col-tile half
    const int w4 = wid & 3;
    const int l16 = lane & 15, quad = lane >> 4;
    const int srow = lane >> 2;
    const int sswz = ((lane & 3) ^ (srow & 3)) << 3;
    const int sA = ((quad ^ (l16 & 3)) << 3);
    const int wm = w4 & 1, wn = w4 >> 1;
    const int Sg = lens[4 * g];           // lengths sorted desc -> group max

    for (int ci = 0; ci < 8; ci++) {
      const int chunk = rev ? (7 - ci) : ci;
      const int t0 = chunk * 32;
      int need = rev ? (Sg - t0 + 1) : (t0 + 33);
      if (t0 >= Sg) need = 0;             // all rows stale (beyond lengths)
      if (need > 0) {
        if (tid == 0) {
          const int target = tagbase + need;     // sentinel tagbase+299 covers all
          for (;;) {
            int mn = 0x7fffffff;
            for (int cbx = 0; cbx < 12; cbx++) {
              int v = ld32_nt(prog + g * 12 + cbx);
              mn = v < mn ? v : mn;
            }
            if (mn >= target) break;
            __builtin_amdgcn_s_sleep(8);
          }
        }
        __syncthreads();
      }
      #pragma unroll 1
      for (int cpi = 0; cpi < 2; cpi++) {
        const int cp = 2 * q + cpi;       // 0..7 (256 cols each)
        const unsigned short* BtB = Bt_next + (size_t)(cp * 256 + wg * 128) * KP;
        f32x4 acc[4][4] = {};
        for (int kc = 0; kc < 10; kc++) {
          const int k0 = kc << 5;
          {
            int rl = wid * 16 + srow;     // local row 0..127
            int xrow = (t0 + (rl >> 2)) * 64 + g * 4 + (rl & 3);
            gl_lds16(xb + (size_t)xrow * KP + k0 + sswz, &As[(wid * 16) * 32]);
          }
          #pragma unroll
          for (int r = 0; r < 2; r++) {
            int rbase = w4 * 32 + r * 16;
            gl_lds16(BtB + (size_t)(rbase + srow) * KP + k0 + sswz, &Bs2[wg][rbase * 32]);
          }
          asm volatile("s_waitcnt vmcnt(0)" ::: "memory");
          __syncthreads();
          bf16x8 af[4], bfr[4];
          #pragma unroll
          for (int i = 0; i < 4; i++) {
            af[i]  = *(const bf16x8*)&As[(wm * 64 + i * 16 + l16) * 32 + sA];
            bfr[i] = *(const bf16x8*)&Bs2[wg][(wn * 64 + i * 16 + l16) * 32 + sA];
          }
          #pragma unroll
          for (int mi = 0; mi < 4; mi++)
            #pragma unroll
            for (int ni = 0; ni < 4; ni++)
              acc[mi][ni] = __builtin_amdgcn_mfma_f32_16x16x32_bf16(af[mi], bfr[ni], acc[mi][ni], 0, 0, 0);
          __syncthreads();
        }
        #pragma unroll
        for (int mi = 0; mi < 4; mi++) {
          #pragma unroll
          for (int ni = 0; ni < 4; ni++) {
            int col = cp * 256 + wg * 128 + wn * 64 + ni * 16 + l16;
            if (col < NG) {
              #pragma unroll
              for (int i = 0; i < 4; i++) {
                int rl = wm * 64 + mi * 16 + quad * 4 + i;
                int prow = (t0 + (rl >> 2)) * 64 + g * 4 + (rl & 3);
                pi[(size_t)prow * NG + col] = acc[mi][ni][i];
              }
            }
          }
        }
      }
    }
  }
}

extern "C" void kernel_launch(void* const* d_in, const int* in_sizes, int n_in,
                              void* d_out, int out_size, void* d_ws, size_t ws_size,
                              hipStream_t stream) {
  const float* inputs = (const float*)d_in[0];
  const int* lengths = (const int*)d_in[1];
  const float* W_ih0 = (const float*)d_in[2];
  const float* W_ih_rest = (const float*)d_in[3];
  const float* W_hh = (const float*)d_in[4];
  const float* b_hh = (const float*)d_in[5];
  float* outp = (float*)d_out;
  float* hidden = outp + (size_t)B_ * T_ * H_;   // [L][T,B,H]

  char* ws = (char*)d_ws;
  float* pi = (float*)ws;                                         // M_*NG fp32 (118MB)
  size_t off = (size_t)M_ * NG * 4;
  unsigned short* xb = (unsigned short*)(ws + off);               // M_*KP bf16 (10.5MB)
  off += (size_t)M_ * KP * 2;
  unsigned short* WbT = (unsigned short*)(ws + off);              // 8*NBP*KP bf16 (10.5MB)
  off += (size_t)L_ * NBP * KP * 2;
  ull* h_words = (ull*)(ws + off);   // fast[16][1200] + slow[16][1200] u64 + prog[16][12]
  size_t data_bytes = 32ull * 1200 * 8;
  int* prog = (int*)(ws + off + data_bytes);
  size_t hw_bytes = data_bytes + 16ull * 12 * 4;
  off += hw_bytes;

  hipMemsetAsync(d_out, 0, (size_t)out_size * 4, stream);         // zero padding regions
  hipMemsetAsync(h_words, 0, hw_bytes, stream);                   // clear tags + prog
  hipMemsetAsync(xb, 0, (size_t)M_ * KP * 2, stream);             // zero K padding
  hipMemsetAsync(WbT, 0, (size_t)L_ * NBP * KP * 2, stream);      // zero N/K padding

  k_transpose_w<<<dim3(29, 5, 8), 256, 0, stream>>>(W_ih0, W_ih_rest, WbT);
  {
    int n = T_ * B_ * D_;
    k_transpose_in<<<(n + 255) / 256, 256, 0, stream>>>(inputs, xb);
  }
  // layer-0 pi: standalone GEMM (K=200 -> nk=7)
  k_gemm<<<dim3(M_ / 128, 15), 256, 0, stream>>>(xb, WbT, pi, 7);
  for (int l = 0; l < L_; l++) {
    float* hid_l = hidden + (size_t)l * T_ * B_ * H_;
    const unsigned short* Bt_next = WbT + (size_t)(l + 1) * NBP * KP;  // unused when l==7
    int grid = (l < L_ - 1) ? 256 : 192;
    k_fused<<<grid, 512, 0, stream>>>(pi, W_hh + (size_t)l * H_ * NZ, b_hh + (size_t)l * NZ,
                                      lengths, hid_l, xb, h_words, prog,
                                      Bt_next, l & 1, l * 300);
  }
  k_out<<<((B_ * T_ * H_) + 255) / 256, 256, 0, stream>>>(
      hidden + (size_t)(L_ - 1) * T_ * B_ * H_, outp);
}